// Round 1
// 6999.426 us; speedup vs baseline: 2.3107x; 2.3107x over previous
//
#include <hip/hip_runtime.h>

#define BATCH 8192
#define DIN   4096
#define HID   16384
#define KTOP  64

// ---------------- GEMM NT fp32 (kept for fallback paths only) ----------------
#define BM 128
#define BN 128
#define BKK 8
#define TM 8
#define TN 8

__global__ __launch_bounds__(256)
void gemm_nt_kernel(const float* __restrict__ A, const float* __restrict__ Bm,
                    const float* __restrict__ bias, float* __restrict__ C,
                    int M, int N, int K, int doRelu)
{
    __shared__ float As[BKK][BM + 4];
    __shared__ float Bs[BKK][BN + 4];
    const int tid = threadIdx.x;
    const int m0 = blockIdx.y * BM;
    const int n0 = blockIdx.x * BN;
    const int tr = tid >> 4;
    const int tc = tid & 15;
    const int lar = tid >> 1;
    const int lac = (tid & 1) * 4;

    const float* Aload = A + (size_t)(m0 + lar) * K + lac;
    const float* Bload = Bm + (size_t)(n0 + lar) * K + lac;

    float acc[TM][TN];
    #pragma unroll
    for (int i = 0; i < TM; ++i)
        #pragma unroll
        for (int j = 0; j < TN; ++j) acc[i][j] = 0.f;

    for (int k0 = 0; k0 < K; k0 += BKK) {
        float4 a4 = *(const float4*)(Aload + k0);
        float4 b4 = *(const float4*)(Bload + k0);
        As[lac + 0][lar] = a4.x; As[lac + 1][lar] = a4.y;
        As[lac + 2][lar] = a4.z; As[lac + 3][lar] = a4.w;
        Bs[lac + 0][lar] = b4.x; Bs[lac + 1][lar] = b4.y;
        Bs[lac + 2][lar] = b4.z; Bs[lac + 3][lar] = b4.w;
        __syncthreads();
        #pragma unroll
        for (int kk = 0; kk < BKK; ++kk) {
            float af[TM], bf[TN];
            #pragma unroll
            for (int i = 0; i < TM; ++i) af[i] = As[kk][tr * TM + i];
            #pragma unroll
            for (int j = 0; j < TN; ++j) bf[j] = Bs[kk][tc * TN + j];
            #pragma unroll
            for (int i = 0; i < TM; ++i)
                #pragma unroll
                for (int j = 0; j < TN; ++j)
                    acc[i][j] = fmaf(af[i], bf[j], acc[i][j]);
        }
        __syncthreads();
    }

    float bv[TN];
    #pragma unroll
    for (int j = 0; j < TN; ++j) bv[j] = bias ? bias[n0 + tc * TN + j] : 0.f;
    #pragma unroll
    for (int i = 0; i < TM; ++i) {
        float* crow = C + (size_t)(m0 + tr * TM + i) * N + n0 + tc * TN;
        #pragma unroll
        for (int j = 0; j < TN; ++j) {
            float v = acc[i][j] + bv[j];
            if (doRelu) v = v > 0.f ? v : 0.f;
            crow[j] = v;
        }
    }
}

// ---------------- MFMA split-bf16 GEMM NT: C = act(A*B^T + bias) ----------------
// fp32 inputs split on the fly: a = a_hi + a_lo (hi = trunc-to-bf16, lo = rne(residual)).
// acc += ah*bh + al*bh + ah*bl  (fp32 MFMA accumulation; dropped lo*lo ~ 2^-16 rel).
// Tile 128x128, BK=32 (fp32 K), 4 waves of 64x64, mfma_f32_16x16x32_bf16.
// LDS rows interleave hi|lo -> 128B row stride; XOR-swizzle bits 4-6 by (row&7)
// makes all ds_read_b128 fragment reads bank-conflict-free (T2 pattern).

typedef __bf16 bf16x8 __attribute__((ext_vector_type(8)));
typedef float  f32x4  __attribute__((ext_vector_type(4)));

__device__ __forceinline__ unsigned swz(unsigned L) {
    return L ^ (((L >> 7) & 7u) << 4);          // row stride = 128B; XOR within row
}

__device__ __forceinline__ unsigned rne_bf16(unsigned u) {
    return (u + 0x7fffu + ((u >> 16) & 1u)) >> 16;
}

__device__ __forceinline__ void cvt4(const float4 v, unsigned& h01, unsigned& h23,
                                     unsigned& l01, unsigned& l23)
{
    unsigned ux = __float_as_uint(v.x), uy = __float_as_uint(v.y);
    unsigned uz = __float_as_uint(v.z), uw = __float_as_uint(v.w);
    unsigned hx = ux & 0xffff0000u, hy = uy & 0xffff0000u;
    unsigned hz = uz & 0xffff0000u, hw = uw & 0xffff0000u;
    h01 = (hx >> 16) | hy;                       // low short = element k (x)
    h23 = (hz >> 16) | hw;
    float rx = v.x - __uint_as_float(hx);        // exact residual (low mantissa bits)
    float ry = v.y - __uint_as_float(hy);
    float rz = v.z - __uint_as_float(hz);
    float rw = v.w - __uint_as_float(hw);
    l01 = rne_bf16(__float_as_uint(rx)) | (rne_bf16(__float_as_uint(ry)) << 16);
    l23 = rne_bf16(__float_as_uint(rz)) | (rne_bf16(__float_as_uint(rw)) << 16);
}

__global__ __launch_bounds__(256, 2)
void gemm_mfma_split_kernel(const float* __restrict__ A, const float* __restrict__ Bm,
                            const float* __restrict__ bias, float* __restrict__ C,
                            int M, int N, int K, int doRelu)
{
    __shared__ short Ahl[128 * 64];   // [row 0..127][ hi k0..31 | lo k0..31 ]  16KB
    __shared__ short Bhl[128 * 64];   // same, 16KB

    const int tid = threadIdx.x;

    // XCD-aware bijective block swizzle (grid is a multiple of 8 blocks here)
    const int nbx = gridDim.x;
    const int nwg = nbx * gridDim.y;
    int lin = blockIdx.y * nbx + blockIdx.x;
    int tl  = ((nwg & 7) == 0) ? ((lin & 7) * (nwg >> 3) + (lin >> 3)) : lin;
    const int m0 = (tl / nbx) * 128;
    const int n0 = (tl % nbx) * 128;

    // ---- staging map: thread -> (rows rA+32j, fp32 cols c4*4..+3) ----
    const int rA = tid >> 3;                 // 0..31
    const int c4 = tid & 7;                  // 0..7
    const size_t aRow  = (size_t)(m0 + rA) * K + c4 * 4;
    const size_t bRow  = (size_t)(n0 + rA) * K + c4 * 4;
    const size_t jstep = (size_t)32 * K;
    const unsigned wHi = swz((unsigned)(rA * 128 + c4 * 8));
    const unsigned wLo = swz((unsigned)(rA * 128 + 64 + c4 * 8));

    // ---- fragment map: wave (wr,wc) owns a 64x64 sub-tile ----
    const int lane = tid & 63;
    const int w  = tid >> 6;
    const int wr = w >> 1, wc = w & 1;
    const int c  = lane & 15;                // M/N index within 16x16 fragment
    const int q  = lane >> 4;                // k-chunk 0..3 (8 bf16 each)
    const unsigned aHi = swz((unsigned)((wr * 64 + c) * 128 + q * 16));
    const unsigned aLo = swz((unsigned)((wr * 64 + c) * 128 + 64 + q * 16));
    const unsigned bHi = swz((unsigned)((wc * 64 + c) * 128 + q * 16));
    const unsigned bLo = swz((unsigned)((wc * 64 + c) * 128 + 64 + q * 16));

    f32x4 acc[4][4];
    #pragma unroll
    for (int mi = 0; mi < 4; ++mi)
        #pragma unroll
        for (int ni = 0; ni < 4; ++ni) acc[mi][ni] = f32x4{0.f, 0.f, 0.f, 0.f};

    // prologue: load K-tile 0 into registers
    float4 pa[4], pb[4];
    #pragma unroll
    for (int j = 0; j < 4; ++j) {
        pa[j] = *(const float4*)(A  + aRow + j * jstep);
        pb[j] = *(const float4*)(Bm + bRow + j * jstep);
    }

    const int nkt = K >> 5;                   // BK = 32 fp32
    for (int kt = 0; kt < nkt; ++kt) {
        // split + stage current tile to LDS
        #pragma unroll
        for (int j = 0; j < 4; ++j) {
            unsigned h01, h23, l01, l23;
            cvt4(pa[j], h01, h23, l01, l23);
            *(uint2*)((char*)Ahl + wHi + j * 4096) = make_uint2(h01, h23);
            *(uint2*)((char*)Ahl + wLo + j * 4096) = make_uint2(l01, l23);
            cvt4(pb[j], h01, h23, l01, l23);
            *(uint2*)((char*)Bhl + wHi + j * 4096) = make_uint2(h01, h23);
            *(uint2*)((char*)Bhl + wLo + j * 4096) = make_uint2(l01, l23);
        }
        // issue next tile's global loads now; latency hides under MFMA phase
        if (kt + 1 < nkt) {
            const size_t ko = (size_t)(kt + 1) * 32;
            #pragma unroll
            for (int j = 0; j < 4; ++j) {
                pa[j] = *(const float4*)(A  + aRow + j * jstep + ko);
                pb[j] = *(const float4*)(Bm + bRow + j * jstep + ko);
            }
        }
        __syncthreads();

        bf16x8 ah[4], alo[4], bh[4], blo[4];
        #pragma unroll
        for (int i = 0; i < 4; ++i) {
            ah[i]  = *(const bf16x8*)((const char*)Ahl + aHi + i * 2048);
            alo[i] = *(const bf16x8*)((const char*)Ahl + aLo + i * 2048);
            bh[i]  = *(const bf16x8*)((const char*)Bhl + bHi + i * 2048);
            blo[i] = *(const bf16x8*)((const char*)Bhl + bLo + i * 2048);
        }
        #pragma unroll
        for (int mi = 0; mi < 4; ++mi)
            #pragma unroll
            for (int ni = 0; ni < 4; ++ni) {
                f32x4 t = acc[mi][ni];
                t = __builtin_amdgcn_mfma_f32_16x16x32_bf16(ah[mi],  bh[ni],  t, 0, 0, 0);
                t = __builtin_amdgcn_mfma_f32_16x16x32_bf16(alo[mi], bh[ni],  t, 0, 0, 0);
                t = __builtin_amdgcn_mfma_f32_16x16x32_bf16(ah[mi],  blo[ni], t, 0, 0, 0);
                acc[mi][ni] = t;
            }
        __syncthreads();
    }

    // epilogue: D[row = q*4+i][col = c] per fragment (m89-verified C/D layout)
    const int cN = n0 + wc * 64 + c;
    float bvv[4];
    #pragma unroll
    for (int ni = 0; ni < 4; ++ni) bvv[ni] = bias ? bias[cN + ni * 16] : 0.f;
    #pragma unroll
    for (int mi = 0; mi < 4; ++mi) {
        #pragma unroll
        for (int i = 0; i < 4; ++i) {
            float* cp = C + (size_t)(m0 + wr * 64 + mi * 16 + q * 4 + i) * N + cN;
            #pragma unroll
            for (int ni = 0; ni < 4; ++ni) {
                float v = acc[mi][ni][i] + bvv[ni];
                if (doRelu) v = v > 0.f ? v : 0.f;
                cp[ni * 16] = v;
            }
        }
    }
}

// ---------------- Selection stage 1: fp32 kth value, window candidates ----------------
#define NB 4096
#define MAXC 2048
#define CAP 32
#define EPSW 4.0e-3f

__global__ __launch_bounds__(256)
void topk_select_kernel(float* __restrict__ F, float* __restrict__ pv, int* __restrict__ pi,
                        int* __restrict__ candIdx, float* __restrict__ candVal,
                        int* __restrict__ candCnt, int* __restrict__ acnt)
{
    __shared__ unsigned hist[NB];
    __shared__ unsigned tsum[256];
    __shared__ float bcv[MAXC];
    __shared__ int   bci[MAXC];
    __shared__ int sb_star, sAcnt, snb, sPair, sCand, sselAll;
    __shared__ float sfk;

    const int b = blockIdx.x;
    const int t = threadIdx.x;
    float* row = F + (size_t)b * HID;

    float v[64];
    #pragma unroll
    for (int i = 0; i < 64; ++i) v[i] = row[t + i * 256];

    #pragma unroll
    for (int i = 0; i < NB / 256; ++i) hist[t + i * 256] = 0;
    if (t == 0) { snb = 0; sPair = 0; sCand = 0; sb_star = -1; sAcnt = 0; sselAll = 0; sfk = 0.f; }
    __syncthreads();

    #pragma unroll
    for (int i = 0; i < 64; ++i) {
        float val = v[i];
        if (val > 0.f) atomicAdd(&hist[__float_as_uint(val) >> 19], 1u);
    }
    __syncthreads();

    unsigned own = 0;
    #pragma unroll
    for (int j = 0; j < 16; ++j) own += hist[t * 16 + j];
    tsum[t] = own;
    __syncthreads();
    for (int off = 1; off < 256; off <<= 1) {
        unsigned add = (t + off < 256) ? tsum[t + off] : 0u;
        __syncthreads();
        tsum[t] += add;
        __syncthreads();
    }
    const unsigned total = tsum[0];
    const unsigned above_chunk = tsum[t] - own;
    if (t == 0 && total <= (unsigned)KTOP) sselAll = 1;

    if (total > (unsigned)KTOP) {
        unsigned run = above_chunk;
        for (int j = 15; j >= 0; --j) {
            unsigned c = hist[t * 16 + j];
            if (run < KTOP && run + c >= KTOP) { sb_star = t * 16 + j; sAcnt = (int)run; }
            run += c;
        }
    }
    __syncthreads();

    if (sselAll) {
        #pragma unroll
        for (int i = 0; i < 64; ++i) {
            float val = v[i];
            if (val > 0.f) {
                int p = atomicAdd(&sPair, 1);
                pv[(size_t)b * KTOP + p] = val;
                pi[(size_t)b * KTOP + p] = t + i * 256;
            }
        }
        __syncthreads();
        int ns = sPair;
        if (t < KTOP && t >= ns) { pv[(size_t)b * KTOP + t] = 0.f; pi[(size_t)b * KTOP + t] = 0; }
        if (t == 0) { acnt[b] = ns; candCnt[b] = 0; }
        return;
    }

    const int bstar = sb_star;
    const int Acnt  = sAcnt;
    const int need  = KTOP - Acnt;

    #pragma unroll
    for (int i = 0; i < 64; ++i) {
        float val = v[i];
        if (val > 0.f && (int)(__float_as_uint(val) >> 19) == bstar) {
            int p = atomicAdd(&snb, 1);
            if (p < MAXC) { bcv[p] = val; bci[p] = t + i * 256; }
        }
    }
    __syncthreads();
    int nb = snb; if (nb > MAXC) nb = MAXC;

    for (int c = t; c < nb; c += 256) {
        float mv = bcv[c]; int mi = bci[c];
        int r = 0;
        for (int c2 = 0; c2 < nb; ++c2) {
            float ov = bcv[c2];
            if (ov > mv || (ov == mv && bci[c2] < mi)) ++r;
        }
        if (r == need - 1) sfk = mv;
    }
    __syncthreads();

    const float fk = sfk;
    const float hi = fk + EPSW;
    const float lo = fk - EPSW;

    #pragma unroll
    for (int i = 0; i < 64; ++i) {
        float val = v[i];
        int idx = t + i * 256;
        if (val > hi) {
            int p = atomicAdd(&sPair, 1);
            pv[(size_t)b * KTOP + p] = val;
            pi[(size_t)b * KTOP + p] = idx;
        } else if (val >= lo && val > 0.f) {
            int c = atomicAdd(&sCand, 1);
            if (c < CAP) {
                candIdx[(size_t)b * CAP + c] = idx;
                candVal[(size_t)b * CAP + c] = val;
            }
            row[idx] = 0.f;
        } else if (val != 0.f) {
            row[idx] = 0.f;
        }
    }
    __syncthreads();
    if (t == 0) {
        acnt[b] = sPair;
        int c = sCand; if (c > CAP) c = CAP;
        candCnt[b] = c;
    }
}

// ---------------- Selection stage 2: fp64 recompute of window candidates ----------------
__global__ __launch_bounds__(256)
void refine_kernel(const float* __restrict__ x, const float* __restrict__ W,
                   const float* __restrict__ be,
                   const int* __restrict__ candIdx, const int* __restrict__ candCnt,
                   double* __restrict__ refined)
{
    const int lane = threadIdx.x & 63;
    const int wave = threadIdx.x >> 6;
    const int task = blockIdx.x * 4 + wave;
    const int b = task >> 5;
    const int slot = task & (CAP - 1);
    if (slot >= candCnt[b]) return;
    const int h = candIdx[(size_t)b * CAP + slot];
    const float* xr = x + (size_t)b * DIN;
    const float* wr = W + (size_t)h * DIN;
    double acc = 0.0;
    #pragma unroll 8
    for (int i = 0; i < DIN / 64; ++i)
        acc += (double)xr[lane + 64 * i] * (double)wr[lane + 64 * i];
    #pragma unroll
    for (int off = 32; off > 0; off >>= 1)
        acc += __shfl_down(acc, off, 64);
    if (lane == 0) refined[(size_t)b * CAP + slot] = acc + (double)be[h];
}

// ---------------- Selection stage 3: rank window by fp64, finalize ----------------
__global__ __launch_bounds__(64)
void finalize_kernel(float* __restrict__ F,
                     const int* __restrict__ candIdx, const float* __restrict__ candVal,
                     const double* __restrict__ refined,
                     const int* __restrict__ candCnt, const int* __restrict__ acnt,
                     float* __restrict__ pv, int* __restrict__ pi)
{
    const int b = blockIdx.x;
    const int t = threadIdx.x;
    const int A = acnt[b];
    const int cnt = candCnt[b];
    int need = KTOP - A; if (need < 0) need = 0;

    if (t >= A) { pv[(size_t)b * KTOP + t] = 0.f; pi[(size_t)b * KTOP + t] = 0; }
    __syncthreads();

    if (t < cnt) {
        double mv = refined[(size_t)b * CAP + t];
        int mi = candIdx[(size_t)b * CAP + t];
        int r = 0;
        for (int c2 = 0; c2 < cnt; ++c2) {
            double ov = refined[(size_t)b * CAP + c2];
            if (ov > mv || (ov == mv && candIdx[(size_t)b * CAP + c2] < mi)) ++r;
        }
        if (r < need) {
            float val = candVal[(size_t)b * CAP + t];
            F[(size_t)b * HID + mi] = val;
            pv[(size_t)b * KTOP + A + r] = val;
            pi[(size_t)b * KTOP + A + r] = mi;
        }
    }
}

// ---------------- Transpose W_dec [DIN,HID] -> Wt [HID,DIN] ----------------
__global__ __launch_bounds__(256)
void transpose_kernel(const float* __restrict__ Wd, float* __restrict__ Wt)
{
    __shared__ float tile[32][33];
    const int tx = threadIdx.x;
    const int ty = threadIdx.y;
    const int h = blockIdx.x * 32 + tx;
    const int d0 = blockIdx.y * 32;
    #pragma unroll
    for (int j = 0; j < 32; j += 8)
        tile[ty + j][tx] = Wd[(size_t)(d0 + ty + j) * HID + h];
    __syncthreads();
    const int d = d0 + tx;
    const int h0 = blockIdx.x * 32;
    #pragma unroll
    for (int j = 0; j < 32; j += 8)
        Wt[(size_t)(h0 + ty + j) * DIN + d] = tile[tx][ty + j];
}

// ---------------- Sparse decode: R[b,:] = sum_j val_j * Wt[idx_j,:] ----------------
__global__ __launch_bounds__(256)
void decode_kernel(const float* __restrict__ pv, const int* __restrict__ pi,
                   const float* __restrict__ Wt, float* __restrict__ R)
{
    __shared__ float sval[KTOP];
    __shared__ int   sidx[KTOP];
    const int b = blockIdx.x;
    const int t = threadIdx.x;
    if (t < KTOP) { sval[t] = pv[(size_t)b * KTOP + t]; sidx[t] = pi[(size_t)b * KTOP + t]; }
    __syncthreads();

    float4 acc[4];
    #pragma unroll
    for (int i = 0; i < 4; ++i) acc[i] = make_float4(0.f, 0.f, 0.f, 0.f);

    for (int j = 0; j < KTOP; ++j) {
        float vv = sval[j];
        if (vv == 0.f) continue;
        const float4* wr = (const float4*)(Wt + (size_t)sidx[j] * DIN);
        #pragma unroll
        for (int i = 0; i < 4; ++i) {
            float4 w = wr[t + i * 256];
            acc[i].x = fmaf(vv, w.x, acc[i].x);
            acc[i].y = fmaf(vv, w.y, acc[i].y);
            acc[i].z = fmaf(vv, w.z, acc[i].z);
            acc[i].w = fmaf(vv, w.w, acc[i].w);
        }
    }
    float4* out = (float4*)(R + (size_t)b * DIN);
    #pragma unroll
    for (int i = 0; i < 4; ++i) out[t + i * 256] = acc[i];
}

// ---------------- fallback exact-fp32 topk (only if ws too small) ----------------
__global__ __launch_bounds__(256)
void topk_fp32_kernel(float* __restrict__ F)
{
    __shared__ unsigned hist[NB];
    __shared__ unsigned tsum[256];
    __shared__ float bcv[MAXC];
    __shared__ int   bci[MAXC];
    __shared__ unsigned char csel[MAXC];
    __shared__ int sb_star, sAcnt, snb, sselAll;

    const int b = blockIdx.x;
    const int t = threadIdx.x;
    float* row = F + (size_t)b * HID;
    float v[64];
    #pragma unroll
    for (int i = 0; i < 64; ++i) v[i] = row[t + i * 256];
    #pragma unroll
    for (int i = 0; i < NB / 256; ++i) hist[t + i * 256] = 0;
    if (t == 0) { snb = 0; sb_star = -1; sAcnt = 0; sselAll = 0; }
    __syncthreads();
    #pragma unroll
    for (int i = 0; i < 64; ++i)
        if (v[i] > 0.f) atomicAdd(&hist[__float_as_uint(v[i]) >> 19], 1u);
    __syncthreads();
    unsigned own = 0;
    #pragma unroll
    for (int j = 0; j < 16; ++j) own += hist[t * 16 + j];
    tsum[t] = own;
    __syncthreads();
    for (int off = 1; off < 256; off <<= 1) {
        unsigned add = (t + off < 256) ? tsum[t + off] : 0u;
        __syncthreads();
        tsum[t] += add;
        __syncthreads();
    }
    const unsigned total = tsum[0];
    const unsigned above_chunk = tsum[t] - own;
    if (t == 0 && total <= (unsigned)KTOP) sselAll = 1;
    if (total > (unsigned)KTOP) {
        unsigned run = above_chunk;
        for (int j = 15; j >= 0; --j) {
            unsigned c = hist[t * 16 + j];
            if (run < KTOP && run + c >= KTOP) { sb_star = t * 16 + j; sAcnt = (int)run; }
            run += c;
        }
    }
    __syncthreads();
    if (sselAll) return;
    const int bstar = sb_star;
    const int need = KTOP - sAcnt;
    #pragma unroll
    for (int i = 0; i < 64; ++i) {
        float val = v[i];
        if (val > 0.f && (int)(__float_as_uint(val) >> 19) == bstar) {
            int p = atomicAdd(&snb, 1);
            if (p < MAXC) { bcv[p] = val; bci[p] = t + i * 256; }
        }
    }
    __syncthreads();
    int nb = snb; if (nb > MAXC) nb = MAXC;
    for (int c = t; c < nb; c += 256) {
        float mv = bcv[c]; int mi = bci[c];
        int r = 0;
        for (int c2 = 0; c2 < nb; ++c2) {
            float ov = bcv[c2];
            if (ov > mv || (ov == mv && bci[c2] < mi)) ++r;
        }
        csel[c] = (r < need) ? 1 : 0;
    }
    __syncthreads();
    #pragma unroll
    for (int i = 0; i < 64; ++i) {
        float val = v[i];
        int idx = t + i * 256;
        bool keep = false;
        if (val > 0.f) {
            int key = (int)(__float_as_uint(val) >> 19);
            if (key > bstar) keep = true;
            else if (key == bstar)
                for (int c2 = 0; c2 < nb; ++c2)
                    if (bci[c2] == idx) { keep = (csel[c2] != 0); break; }
        }
        if (!keep && val != 0.f) row[idx] = 0.f;
    }
}

extern "C" void kernel_launch(void* const* d_in, const int* in_sizes, int n_in,
                              void* d_out, int out_size, void* d_ws, size_t ws_size,
                              hipStream_t stream)
{
    const float* x     = (const float*)d_in[0];
    const float* W_enc = (const float*)d_in[1];
    const float* b_enc = (const float*)d_in[2];
    const float* W_dec = (const float*)d_in[3];

    float* sparse = (float*)d_out;                      // [BATCH, HID]
    float* recon  = sparse + (size_t)BATCH * HID;       // [BATCH, DIN]

    // workspace layout
    char* p = (char*)d_ws;
    size_t off = 0;
    float* pv      = (float*)(p + off); off += (size_t)BATCH * KTOP * 4;
    int*   pi      = (int*)  (p + off); off += (size_t)BATCH * KTOP * 4;
    int*   candIdx = (int*)  (p + off); off += (size_t)BATCH * CAP * 4;
    float* candVal = (float*)(p + off); off += (size_t)BATCH * CAP * 4;
    double* refined= (double*)(p + off); off += (size_t)BATCH * CAP * 8;
    int*   candCnt = (int*)  (p + off); off += (size_t)BATCH * 4;
    int*   acnt    = (int*)  (p + off); off += (size_t)BATCH * 4;
    const size_t selBytes = off;
    float* Wt      = (float*)(p + off); off += (size_t)HID * DIN * 4;
    const int haveSel = (ws_size >= selBytes) ? 1 : 0;
    const int haveWt  = (ws_size >= off) ? 1 : 0;

    // 1) dense encoder features via split-bf16 MFMA (fp32-equivalent to ~1e-5)
    gemm_mfma_split_kernel<<<dim3(HID / 128, BATCH / 128), 256, 0, stream>>>(
        x, W_enc, b_enc, sparse, BATCH, HID, DIN, 1);

    if (haveSel) {
        // 2) fp32 kth + boundary window
        topk_select_kernel<<<BATCH, 256, 0, stream>>>(sparse, pv, pi, candIdx, candVal,
                                                      candCnt, acnt);
        // 3) fp64 recompute of window candidates
        refine_kernel<<<BATCH * CAP / 4, 256, 0, stream>>>(x, W_enc, b_enc,
                                                           candIdx, candCnt, refined);
        // 4) final ranking by fp64, restore winners, finish pair list
        finalize_kernel<<<BATCH, 64, 0, stream>>>(sparse, candIdx, candVal, refined,
                                                  candCnt, acnt, pv, pi);
        // 5) decode
        if (haveWt) {
            transpose_kernel<<<dim3(HID / 32, DIN / 32), dim3(32, 8), 0, stream>>>(W_dec, Wt);
            decode_kernel<<<BATCH, 256, 0, stream>>>(pv, pi, Wt, recon);
        } else {
            gemm_nt_kernel<<<dim3(DIN / BN, BATCH / BM), 256, 0, stream>>>(
                sparse, W_dec, nullptr, recon, BATCH, DIN, HID, 0);
        }
    } else {
        topk_fp32_kernel<<<BATCH, 256, 0, stream>>>(sparse);
        gemm_nt_kernel<<<dim3(DIN / BN, BATCH / BM), 256, 0, stream>>>(
            sparse, W_dec, nullptr, recon, BATCH, DIN, HID, 0);
    }
}